// Round 9
// baseline (397.511 us; speedup 1.0000x reference)
//
#include <hip/hip_runtime.h>
#include <cstdint>

typedef double d4 __attribute__((ext_vector_type(4)));

// ---------------------------------------------------------------------------
// SNN: 64-step scan over 3 spike-gated linear layers, all internal math f64.
// GEMM uses v_mfma_f64_16x16x4_f64 with an on-device-probed fragment layout
// (round-4 lesson: f64 MFMA layout differs from the bf16 family).
// Round-5: depth-2 pipeline (3 SSA register sets) lifted MfmaUtil 35->64%.
// Round-7: smaller steps + more waves regressed (48%) -> per-step MFMA:load
// ratio matters; Round-8: j=64/wave, 16 MFMA/step -> 66%, but grid gave only
// 2 waves/SIMD (occupancy 20%). Round-9 experiment: C=48 -> 3 waves/SIMD
// (register-feasible at 156 regs) to cover simultaneous load-wait windows.
// ---------------------------------------------------------------------------

__global__ __launch_bounds__(64) void k_probe(int* __restrict__ lut)
{
    int l = threadIdx.x;
    d4 z = {0.0, 0.0, 0.0, 0.0};
    d4 d1 = __builtin_amdgcn_mfma_f64_16x16x4f64(1.0, (double)l, z, 0, 0, 0);
    d4 d2 = __builtin_amdgcn_mfma_f64_16x16x4f64((double)l, 1.0, z, 0, 0, 0);
    int amode = 0, bmode = 0;
    int rw[4], cl[4];
#pragma unroll
    for (int r = 0; r < 4; ++r) {
        int v1 = (int)(d1[r] + 0.5);
        if ((v1 & 3) == 0) { cl[r] = (v1 - 96) >> 2; bmode = 0; }
        else               { cl[r] = (v1 - 6) >> 4;  bmode = 1; }
        int v2 = (int)(d2[r] + 0.5);
        if ((v2 & 3) == 0) { rw[r] = (v2 - 96) >> 2; amode = 0; }
        else               { rw[r] = (v2 - 6) >> 4;  amode = 1; }
    }
    {
        int m = l >> 2, k = l & 3;
        lut[l] = (amode == 0) ? (m + (k << 4)) : ((m << 2) + k);
    }
    lut[64 + l]  = (bmode == 0) ? (l >> 4) : (l & 3);
    lut[128 + l] = (bmode == 0) ? (l & 15) : (l >> 2);
#pragma unroll
    for (int r = 0; r < 4; ++r) {
        lut[192 + (r << 6) + l] = rw[r];
        lut[448 + (r << 6) + l] = cl[r];
    }
}

// SA block layout: SA[i>>2][tt=t>>4][ lane = lutAinv[(t&15)*4 + (i&3)] ]
__global__ __launch_bounds__(256) void k_input(const float* __restrict__ img,
                                               float* __restrict__ out0, // 65 x n
                                               double* __restrict__ SA0,
                                               const int* __restrict__ lut, int n)
{
    int i = blockIdx.x * 256 + threadIdx.x;
    if (i >= n) return;
    int lanes[16];
#pragma unroll
    for (int m = 0; m < 16; ++m) lanes[m] = lut[(m << 2) + (i & 3)];
    double* base = SA0 + ((size_t)(i >> 2) << 8);
    double m = 0.0;
    double x = (double)img[i];
#pragma unroll
    for (int t = 0; t < 64; ++t) {
        m += x;
        bool fire = (m >= 1.0);
        if (fire) m -= 1.0;          // input layer: no decay
        out0[(size_t)t * n + i] = fire ? 1.0f : 0.0f;
        base[((t >> 4) << 6) + lanes[t & 15]] = fire ? 1.0 : 0.0;
    }
    out0[(size_t)64 * n + i] = 0.0f; // pad_tail: last row zero
}

// MFMA spike-gated GEMM partials: P[c][t][j] = sum_{i in chunk c} S[t][i]*W[i][j]
// Grid: (n_out/64, nchunks). Block = 1 wave (64 threads); wave owns 64 j x 64 t.
// Depth-2 software pipeline, 3 SSA register sets; 16 MFMA + 8 loads per step.
__global__ __launch_bounds__(64) void k_gemm(const float* __restrict__ W,
                                             const double* __restrict__ SA,
                                             double* __restrict__ P,
                                             const int* __restrict__ lut,
                                             int n_in, int n_out, int i_per_chunk)
{
    const int lane = threadIdx.x & 63;
    const int j0   = blockIdx.x * 64;
    const int c    = blockIdx.y;

    const int kB = lut[64 + lane];
    const int nB = lut[128 + lane];
    int rw[4], cl[4];
#pragma unroll
    for (int r = 0; r < 4; ++r) {
        rw[r] = lut[192 + (r << 6) + lane];
        cl[r] = lut[448 + (r << 6) + lane];
    }

    int i0 = c * i_per_chunk;
    int i1 = i0 + i_per_chunk; if (i1 > n_in) i1 = n_in;
    int nsteps = (i1 > i0) ? ((i1 - i0) >> 2) : 0;   // 4 i's per step

    d4 acc[4][4];   // [jt][tt]
#pragma unroll
    for (int jt = 0; jt < 4; ++jt)
#pragma unroll
        for (int tt = 0; tt < 4; ++tt) acc[jt][tt] = (d4){0.0, 0.0, 0.0, 0.0};

    const size_t wstep = (size_t)4 * n_out;          // W elems per step
    const float*  wp0 = W  + (size_t)(i0 + kB) * n_out + j0 + nB;
    const double* ap0 = SA + (((size_t)i0 >> 2) << 8) + lane;

    // three load sets, each serving steps s = k, k+3, k+6, ...
    const float*  Awp = wp0;              const double* Aap = ap0;
    const float*  Bwp = wp0 + wstep;      const double* Bap = ap0 + 256;
    const float*  Cwp = wp0 + 2 * wstep;  const double* Cap = ap0 + 512;
    double Aa0, Aa1, Aa2, Aa3; float Ab0, Ab1, Ab2, Ab3;
    double Ba0, Ba1, Ba2, Ba3; float Bb0, Bb1, Bb2, Bb3;
    double Ca0, Ca1, Ca2, Ca3; float Cb0, Cb1, Cb2, Cb3;

#define LOADSET(S, sidx) do {                                                  \
        if ((sidx) < nsteps) {                                                 \
            S##b0 = S##wp[0];  S##b1 = S##wp[16];                              \
            S##b2 = S##wp[32]; S##b3 = S##wp[48];                              \
            S##a0 = S##ap[0];  S##a1 = S##ap[64];                              \
            S##a2 = S##ap[128]; S##a3 = S##ap[192];                            \
        } else {                                                               \
            S##b0 = 0.f; S##b1 = 0.f; S##b2 = 0.f; S##b3 = 0.f;                \
            S##a0 = 0.0; S##a1 = 0.0; S##a2 = 0.0; S##a3 = 0.0;                \
        }                                                                      \
        S##wp += 3 * wstep; S##ap += 768;                                      \
    } while (0)

#define COMPUTESET(S) do {                                                     \
        double b;                                                              \
        b = (double)S##b0;                                                     \
        acc[0][0] = __builtin_amdgcn_mfma_f64_16x16x4f64(S##a0, b, acc[0][0], 0, 0, 0); \
        acc[0][1] = __builtin_amdgcn_mfma_f64_16x16x4f64(S##a1, b, acc[0][1], 0, 0, 0); \
        acc[0][2] = __builtin_amdgcn_mfma_f64_16x16x4f64(S##a2, b, acc[0][2], 0, 0, 0); \
        acc[0][3] = __builtin_amdgcn_mfma_f64_16x16x4f64(S##a3, b, acc[0][3], 0, 0, 0); \
        b = (double)S##b1;                                                     \
        acc[1][0] = __builtin_amdgcn_mfma_f64_16x16x4f64(S##a0, b, acc[1][0], 0, 0, 0); \
        acc[1][1] = __builtin_amdgcn_mfma_f64_16x16x4f64(S##a1, b, acc[1][1], 0, 0, 0); \
        acc[1][2] = __builtin_amdgcn_mfma_f64_16x16x4f64(S##a2, b, acc[1][2], 0, 0, 0); \
        acc[1][3] = __builtin_amdgcn_mfma_f64_16x16x4f64(S##a3, b, acc[1][3], 0, 0, 0); \
        b = (double)S##b2;                                                     \
        acc[2][0] = __builtin_amdgcn_mfma_f64_16x16x4f64(S##a0, b, acc[2][0], 0, 0, 0); \
        acc[2][1] = __builtin_amdgcn_mfma_f64_16x16x4f64(S##a1, b, acc[2][1], 0, 0, 0); \
        acc[2][2] = __builtin_amdgcn_mfma_f64_16x16x4f64(S##a2, b, acc[2][2], 0, 0, 0); \
        acc[2][3] = __builtin_amdgcn_mfma_f64_16x16x4f64(S##a3, b, acc[2][3], 0, 0, 0); \
        b = (double)S##b3;                                                     \
        acc[3][0] = __builtin_amdgcn_mfma_f64_16x16x4f64(S##a0, b, acc[3][0], 0, 0, 0); \
        acc[3][1] = __builtin_amdgcn_mfma_f64_16x16x4f64(S##a1, b, acc[3][1], 0, 0, 0); \
        acc[3][2] = __builtin_amdgcn_mfma_f64_16x16x4f64(S##a2, b, acc[3][2], 0, 0, 0); \
        acc[3][3] = __builtin_amdgcn_mfma_f64_16x16x4f64(S##a3, b, acc[3][3], 0, 0, 0); \
    } while (0)

    LOADSET(A, 0);
    LOADSET(B, 1);
    LOADSET(C, 2);

    int rounds = (nsteps + 2) / 3;
    int s = 0;
    for (int r = 0; r < rounds; ++r) {
        COMPUTESET(A); LOADSET(A, s + 3);   // consumed 2 compute-steps later
        COMPUTESET(B); LOADSET(B, s + 4);
        COMPUTESET(C); LOADSET(C, s + 5);
        s += 3;
    }
#undef LOADSET
#undef COMPUTESET

    // D element (lane, r) sits at (row rw[r], col cl[r]) of its 16x16 tile.
    double* pc = P + (size_t)c * 64 * n_out;
#pragma unroll
    for (int jt = 0; jt < 4; ++jt)
#pragma unroll
        for (int tt = 0; tt < 4; ++tt)
#pragma unroll
            for (int r = 0; r < 4; ++r)
                pc[(size_t)(tt * 16 + rw[r]) * n_out + (j0 + jt * 16 + cl[r])] = acc[jt][tt][r];
}

// U[t][j] = sum over chunks c of P[c][t][j]  (fixed order: deterministic)
__global__ __launch_bounds__(256) void k_reduceU(const double* __restrict__ P,
                                                 double* __restrict__ U,
                                                 int nchunks, int n_out)
{
    int gid = blockIdx.x * 256 + threadIdx.x;
    int total = 64 * n_out;
    if (gid >= total) return;
    int t = gid / n_out;
    int j = gid - t * n_out;
    double s = 0.0;
    for (int c = 0; c < nchunks; ++c)
        s += P[((size_t)c * 64 + t) * n_out + j];
    U[gid] = s;
}

// Per-neuron membrane scan; emits next layer's spike fragments via the LUT.
// shift=1 => this layer consumes the previous step's spikes (read U[t-1]).
__global__ __launch_bounds__(256) void k_scan(const double* __restrict__ U,
                                              float* __restrict__ outS, // 65 x n_out (pad_head)
                                              double* __restrict__ SAn, // may be null
                                              const int* __restrict__ lut,
                                              int n_out, int shift)
{
    int j = blockIdx.x * 256 + threadIdx.x;
    if (j >= n_out) return;
    int lanes[16];
#pragma unroll
    for (int m = 0; m < 16; ++m) lanes[m] = lut[(m << 2) + (j & 3)];
    double* base = SAn ? (SAn + ((size_t)(j >> 2) << 8)) : (double*)nullptr;
    double m = 0.0;
    outS[j] = 0.0f;                           // row 0 zero (pad_head)
#pragma unroll
    for (int t = 0; t < 64; ++t) {
        int s = t - shift;
        double u = (s >= 0) ? U[(size_t)s * n_out + j] : 0.0;
        m += u;
        bool fire = (m >= 1.0);
        m = fire ? (m - 1.0) : (m * 0.5);
        outS[(size_t)(t + 1) * n_out + j] = fire ? 1.0f : 0.0f;
        if (base) base[((t >> 4) << 6) + lanes[t & 15]] = fire ? 1.0 : 0.0;
    }
}

extern "C" void kernel_launch(void* const* d_in, const int* in_sizes, int n_in_cnt,
                              void* d_out, int out_size, void* d_ws, size_t ws_size,
                              hipStream_t stream)
{
    const float* img = (const float*)d_in[0];
    const float* w1  = (const float*)d_in[1];
    const float* w2  = (const float*)d_in[2];
    const float* w3  = (const float*)d_in[3];

    const int N0 = 16384, N1 = 4096, N2 = 4096, N3 = 1024;

    float* out0 = (float*)d_out;
    float* out1 = out0 + (size_t)65 * N0;
    float* out2 = out1 + (size_t)65 * N1;
    float* out3 = out2 + (size_t)65 * N2;

    // workspace layout
    char* ws = (char*)d_ws;
    const size_t MB = 1024 * 1024;
    double* SA0 = (double*)(ws);               // 16384*64*8 = 8 MiB
    double* SA1 = (double*)(ws + 8 * MB);      //  2 MiB
    double* SA2 = (double*)(ws + 10 * MB);     //  2 MiB
    double* U   = (double*)(ws + 12 * MB);     //  2 MiB
    int*    lut = (int*)   (ws + 14 * MB);     //  2816 B (704 ints)
    double* P   = (double*)(ws + 14 * MB + 4096);

    size_t fixed = 14 * MB + 4096;
    size_t pbudget = (ws_size > fixed) ? (ws_size - fixed) : 0;

    // P bytes per chunk = 64 t x n_out x 8B = 512*n_out
    auto clampi = [](long v, int lo, int hi) { int x = (int)v; if (x < lo) x = lo; if (x > hi) x = hi; return x; };
    int C1 = clampi((long)(pbudget / (512ull * N1)), 1, 48);  // 3072 blocks = 3 waves/SIMD
    int C2 = clampi((long)(pbudget / (512ull * N2)), 1, 48);
    int C3 = clampi((long)(pbudget / (512ull * N3)), 1, 96);  // 1536 blocks

    auto ipc4 = [](int n_in, int C) { return (((n_in + C - 1) / C) + 3) & ~3; };

    // measure the f64 MFMA fragment layout (writes lut; same stream -> ordered)
    k_probe<<<1, 64, 0, stream>>>(lut);

    // layer 0 (input): spikes + fragment-layout S0
    k_input<<<N0 / 256, 256, 0, stream>>>(img, out0, SA0, lut, N0);

    // layer 1: U1 = S0 @ W1 (same-step spikes)
    k_gemm<<<dim3(N1 / 64, C1), 64, 0, stream>>>(w1, SA0, P, lut, N0, N1, ipc4(N0, C1));
    k_reduceU<<<(64 * N1) / 256, 256, 0, stream>>>(P, U, C1, N1);
    k_scan<<<N1 / 256, 256, 0, stream>>>(U, out1, SA1, lut, N1, 0);

    // layer 2: uses previous-step s1
    k_gemm<<<dim3(N2 / 64, C2), 64, 0, stream>>>(w2, SA1, P, lut, N1, N2, ipc4(N1, C2));
    k_reduceU<<<(64 * N2) / 256, 256, 0, stream>>>(P, U, C2, N2);
    k_scan<<<N2 / 256, 256, 0, stream>>>(U, out2, SA2, lut, N2, 1);

    // layer 3: uses previous-step s2
    k_gemm<<<dim3(N3 / 64, C3), 64, 0, stream>>>(w3, SA2, P, lut, N1, N3, ipc4(N1, C3));
    k_reduceU<<<(64 * N3) / 256, 256, 0, stream>>>(P, U, C3, N3);
    k_scan<<<N3 / 256, 256, 0, stream>>>(U, out3, (double*)nullptr, lut, N3, 1);
}

// Round 10
// 363.389 us; speedup vs baseline: 1.0939x; 1.0939x over previous
//
#include <hip/hip_runtime.h>
#include <cstdint>

typedef double d4 __attribute__((ext_vector_type(4)));

// ---------------------------------------------------------------------------
// SNN: 64-step scan over 3 spike-gated linear layers, all internal math f64.
// GEMM uses v_mfma_f64_16x16x4_f64 with an on-device-probed fragment layout
// (round-4 lesson: f64 MFMA layout differs from the bf16 family).
// Residency curve (measured): j=16/72regs/4.2w -> 48%; j=32/120regs/3w -> 64%;
// j=64/220regs/2w(reg-capped) -> 66%. Round-10: the unprobed cell — j=32
// (<=128 regs, 4 waves/SIMD ALLOWED) with grid supplying exactly 4/SIMD:
// C1=C2=32 -> 1024 blocks x 4 waves = 4096 waves = 4/SIMD.
// ---------------------------------------------------------------------------

__global__ __launch_bounds__(64) void k_probe(int* __restrict__ lut)
{
    int l = threadIdx.x;
    d4 z = {0.0, 0.0, 0.0, 0.0};
    d4 d1 = __builtin_amdgcn_mfma_f64_16x16x4f64(1.0, (double)l, z, 0, 0, 0);
    d4 d2 = __builtin_amdgcn_mfma_f64_16x16x4f64((double)l, 1.0, z, 0, 0, 0);
    int amode = 0, bmode = 0;
    int rw[4], cl[4];
#pragma unroll
    for (int r = 0; r < 4; ++r) {
        int v1 = (int)(d1[r] + 0.5);
        if ((v1 & 3) == 0) { cl[r] = (v1 - 96) >> 2; bmode = 0; }
        else               { cl[r] = (v1 - 6) >> 4;  bmode = 1; }
        int v2 = (int)(d2[r] + 0.5);
        if ((v2 & 3) == 0) { rw[r] = (v2 - 96) >> 2; amode = 0; }
        else               { rw[r] = (v2 - 6) >> 4;  amode = 1; }
    }
    {
        int m = l >> 2, k = l & 3;
        lut[l] = (amode == 0) ? (m + (k << 4)) : ((m << 2) + k);
    }
    lut[64 + l]  = (bmode == 0) ? (l >> 4) : (l & 3);
    lut[128 + l] = (bmode == 0) ? (l & 15) : (l >> 2);
#pragma unroll
    for (int r = 0; r < 4; ++r) {
        lut[192 + (r << 6) + l] = rw[r];
        lut[448 + (r << 6) + l] = cl[r];
    }
}

// SA block layout: SA[i>>2][tt=t>>4][ lane = lutAinv[(t&15)*4 + (i&3)] ]
__global__ __launch_bounds__(256) void k_input(const float* __restrict__ img,
                                               float* __restrict__ out0, // 65 x n
                                               double* __restrict__ SA0,
                                               const int* __restrict__ lut, int n)
{
    int i = blockIdx.x * 256 + threadIdx.x;
    if (i >= n) return;
    int lanes[16];
#pragma unroll
    for (int m = 0; m < 16; ++m) lanes[m] = lut[(m << 2) + (i & 3)];
    double* base = SA0 + ((size_t)(i >> 2) << 8);
    double m = 0.0;
    double x = (double)img[i];
#pragma unroll
    for (int t = 0; t < 64; ++t) {
        m += x;
        bool fire = (m >= 1.0);
        if (fire) m -= 1.0;          // input layer: no decay
        out0[(size_t)t * n + i] = fire ? 1.0f : 0.0f;
        base[((t >> 4) << 6) + lanes[t & 15]] = fire ? 1.0 : 0.0;
    }
    out0[(size_t)64 * n + i] = 0.0f; // pad_tail: last row zero
}

// MFMA spike-gated GEMM partials: P[c][t][j] = sum_{i in chunk c} S[t][i]*W[i][j]
// Grid: (n_out/128, nchunks). Block 256 = 4 waves; each wave owns 32 j x 64 t.
// Depth-2 software pipeline, 3 SSA register sets; 8 MFMA + 6 loads per step.
// ~120 unified regs -> 4 waves/SIMD permitted.
__global__ __launch_bounds__(256) void k_gemm(const float* __restrict__ W,
                                              const double* __restrict__ SA,
                                              double* __restrict__ P,
                                              const int* __restrict__ lut,
                                              int n_in, int n_out, int i_per_chunk)
{
    const int lane = threadIdx.x & 63;
    const int wv   = threadIdx.x >> 6;
    const int j0   = blockIdx.x * 128 + wv * 32;
    const int c    = blockIdx.y;

    const int kB = lut[64 + lane];
    const int nB = lut[128 + lane];
    int rw[4], cl[4];
#pragma unroll
    for (int r = 0; r < 4; ++r) {
        rw[r] = lut[192 + (r << 6) + lane];
        cl[r] = lut[448 + (r << 6) + lane];
    }

    int i0 = c * i_per_chunk;
    int i1 = i0 + i_per_chunk; if (i1 > n_in) i1 = n_in;
    int nsteps = (i1 > i0) ? ((i1 - i0) >> 2) : 0;   // 4 i's per step

    d4 acc[2][4];
#pragma unroll
    for (int jt = 0; jt < 2; ++jt)
#pragma unroll
        for (int tt = 0; tt < 4; ++tt) acc[jt][tt] = (d4){0.0, 0.0, 0.0, 0.0};

    const size_t wstep = (size_t)4 * n_out;          // W elems per step
    const float*  wp0 = W  + (size_t)(i0 + kB) * n_out + j0 + nB;
    const double* ap0 = SA + (((size_t)i0 >> 2) << 8) + lane;

    // three load sets, each serving steps s = k, k+3, k+6, ...
    const float*  Awp = wp0;              const double* Aap = ap0;
    const float*  Bwp = wp0 + wstep;      const double* Bap = ap0 + 256;
    const float*  Cwp = wp0 + 2 * wstep;  const double* Cap = ap0 + 512;
    double Aa0, Aa1, Aa2, Aa3; float Ab0, Ab1;
    double Ba0, Ba1, Ba2, Ba3; float Bb0, Bb1;
    double Ca0, Ca1, Ca2, Ca3; float Cb0, Cb1;

#define LOADSET(S, sidx) do {                                                  \
        if ((sidx) < nsteps) {                                                 \
            S##b0 = S##wp[0];  S##b1 = S##wp[16];                              \
            S##a0 = S##ap[0];  S##a1 = S##ap[64];                              \
            S##a2 = S##ap[128]; S##a3 = S##ap[192];                            \
        } else {                                                               \
            S##b0 = 0.f; S##b1 = 0.f;                                          \
            S##a0 = 0.0; S##a1 = 0.0; S##a2 = 0.0; S##a3 = 0.0;                \
        }                                                                      \
        S##wp += 3 * wstep; S##ap += 768;                                      \
    } while (0)

#define COMPUTESET(S) do {                                                     \
        double b0 = (double)S##b0, b1 = (double)S##b1;                         \
        acc[0][0] = __builtin_amdgcn_mfma_f64_16x16x4f64(S##a0, b0, acc[0][0], 0, 0, 0); \
        acc[1][0] = __builtin_amdgcn_mfma_f64_16x16x4f64(S##a0, b1, acc[1][0], 0, 0, 0); \
        acc[0][1] = __builtin_amdgcn_mfma_f64_16x16x4f64(S##a1, b0, acc[0][1], 0, 0, 0); \
        acc[1][1] = __builtin_amdgcn_mfma_f64_16x16x4f64(S##a1, b1, acc[1][1], 0, 0, 0); \
        acc[0][2] = __builtin_amdgcn_mfma_f64_16x16x4f64(S##a2, b0, acc[0][2], 0, 0, 0); \
        acc[1][2] = __builtin_amdgcn_mfma_f64_16x16x4f64(S##a2, b1, acc[1][2], 0, 0, 0); \
        acc[0][3] = __builtin_amdgcn_mfma_f64_16x16x4f64(S##a3, b0, acc[0][3], 0, 0, 0); \
        acc[1][3] = __builtin_amdgcn_mfma_f64_16x16x4f64(S##a3, b1, acc[1][3], 0, 0, 0); \
    } while (0)

    LOADSET(A, 0);
    LOADSET(B, 1);
    LOADSET(C, 2);

    int rounds = (nsteps + 2) / 3;
    int s = 0;
    for (int r = 0; r < rounds; ++r) {
        COMPUTESET(A); LOADSET(A, s + 3);   // consumed 2 compute-steps later
        COMPUTESET(B); LOADSET(B, s + 4);
        COMPUTESET(C); LOADSET(C, s + 5);
        s += 3;
    }
#undef LOADSET
#undef COMPUTESET

    // D element (lane, r) sits at (row rw[r], col cl[r]) of its 16x16 tile.
    double* pc = P + (size_t)c * 64 * n_out;
#pragma unroll
    for (int jt = 0; jt < 2; ++jt)
#pragma unroll
        for (int tt = 0; tt < 4; ++tt)
#pragma unroll
            for (int r = 0; r < 4; ++r)
                pc[(size_t)(tt * 16 + rw[r]) * n_out + (j0 + jt * 16 + cl[r])] = acc[jt][tt][r];
}

// U[t][j] = sum over chunks c of P[c][t][j]  (fixed order: deterministic)
__global__ __launch_bounds__(256) void k_reduceU(const double* __restrict__ P,
                                                 double* __restrict__ U,
                                                 int nchunks, int n_out)
{
    int gid = blockIdx.x * 256 + threadIdx.x;
    int total = 64 * n_out;
    if (gid >= total) return;
    int t = gid / n_out;
    int j = gid - t * n_out;
    double s = 0.0;
    for (int c = 0; c < nchunks; ++c)
        s += P[((size_t)c * 64 + t) * n_out + j];
    U[gid] = s;
}

// Per-neuron membrane scan; emits next layer's spike fragments via the LUT.
// shift=1 => this layer consumes the previous step's spikes (read U[t-1]).
__global__ __launch_bounds__(256) void k_scan(const double* __restrict__ U,
                                              float* __restrict__ outS, // 65 x n_out (pad_head)
                                              double* __restrict__ SAn, // may be null
                                              const int* __restrict__ lut,
                                              int n_out, int shift)
{
    int j = blockIdx.x * 256 + threadIdx.x;
    if (j >= n_out) return;
    int lanes[16];
#pragma unroll
    for (int m = 0; m < 16; ++m) lanes[m] = lut[(m << 2) + (j & 3)];
    double* base = SAn ? (SAn + ((size_t)(j >> 2) << 8)) : (double*)nullptr;
    double m = 0.0;
    outS[j] = 0.0f;                           // row 0 zero (pad_head)
#pragma unroll
    for (int t = 0; t < 64; ++t) {
        int s = t - shift;
        double u = (s >= 0) ? U[(size_t)s * n_out + j] : 0.0;
        m += u;
        bool fire = (m >= 1.0);
        m = fire ? (m - 1.0) : (m * 0.5);
        outS[(size_t)(t + 1) * n_out + j] = fire ? 1.0f : 0.0f;
        if (base) base[((t >> 4) << 6) + lanes[t & 15]] = fire ? 1.0 : 0.0;
    }
}

extern "C" void kernel_launch(void* const* d_in, const int* in_sizes, int n_in_cnt,
                              void* d_out, int out_size, void* d_ws, size_t ws_size,
                              hipStream_t stream)
{
    const float* img = (const float*)d_in[0];
    const float* w1  = (const float*)d_in[1];
    const float* w2  = (const float*)d_in[2];
    const float* w3  = (const float*)d_in[3];

    const int N0 = 16384, N1 = 4096, N2 = 4096, N3 = 1024;

    float* out0 = (float*)d_out;
    float* out1 = out0 + (size_t)65 * N0;
    float* out2 = out1 + (size_t)65 * N1;
    float* out3 = out2 + (size_t)65 * N2;

    // workspace layout
    char* ws = (char*)d_ws;
    const size_t MB = 1024 * 1024;
    double* SA0 = (double*)(ws);               // 16384*64*8 = 8 MiB
    double* SA1 = (double*)(ws + 8 * MB);      //  2 MiB
    double* SA2 = (double*)(ws + 10 * MB);     //  2 MiB
    double* U   = (double*)(ws + 12 * MB);     //  2 MiB
    int*    lut = (int*)   (ws + 14 * MB);     //  2816 B (704 ints)
    double* P   = (double*)(ws + 14 * MB + 4096);

    size_t fixed = 14 * MB + 4096;
    size_t pbudget = (ws_size > fixed) ? (ws_size - fixed) : 0;

    // P bytes per chunk = 64 t x n_out x 8B = 512*n_out
    auto clampi = [](long v, int lo, int hi) { int x = (int)v; if (x < lo) x = lo; if (x > hi) x = hi; return x; };
    int C1 = clampi((long)(pbudget / (512ull * N1)), 1, 32);  // 1024 blocks x 4 waves = 4/SIMD
    int C2 = clampi((long)(pbudget / (512ull * N2)), 1, 32);
    int C3 = clampi((long)(pbudget / (512ull * N3)), 1, 64);  // 512 blocks

    auto ipc4 = [](int n_in, int C) { return (((n_in + C - 1) / C) + 3) & ~3; };

    // measure the f64 MFMA fragment layout (writes lut; same stream -> ordered)
    k_probe<<<1, 64, 0, stream>>>(lut);

    // layer 0 (input): spikes + fragment-layout S0
    k_input<<<N0 / 256, 256, 0, stream>>>(img, out0, SA0, lut, N0);

    // layer 1: U1 = S0 @ W1 (same-step spikes)
    k_gemm<<<dim3(N1 / 128, C1), 256, 0, stream>>>(w1, SA0, P, lut, N0, N1, ipc4(N0, C1));
    k_reduceU<<<(64 * N1) / 256, 256, 0, stream>>>(P, U, C1, N1);
    k_scan<<<N1 / 256, 256, 0, stream>>>(U, out1, SA1, lut, N1, 0);

    // layer 2: uses previous-step s1
    k_gemm<<<dim3(N2 / 128, C2), 256, 0, stream>>>(w2, SA1, P, lut, N1, N2, ipc4(N1, C2));
    k_reduceU<<<(64 * N2) / 256, 256, 0, stream>>>(P, U, C2, N2);
    k_scan<<<N2 / 256, 256, 0, stream>>>(U, out2, SA2, lut, N2, 1);

    // layer 3: uses previous-step s2
    k_gemm<<<dim3(N3 / 128, C3), 256, 0, stream>>>(w3, SA2, P, lut, N1, N3, ipc4(N1, C3));
    k_reduceU<<<(64 * N3) / 256, 256, 0, stream>>>(P, U, C3, N3);
    k_scan<<<N3 / 256, 256, 0, stream>>>(U, out3, (double*)nullptr, lut, N3, 1);
}

// Round 11
// 348.719 us; speedup vs baseline: 1.1399x; 1.0421x over previous
//
#include <hip/hip_runtime.h>
#include <cstdint>

typedef double d4 __attribute__((ext_vector_type(4)));

// ---------------------------------------------------------------------------
// SNN: 64-step scan over 3 spike-gated linear layers, all internal math f64.
// GEMM uses v_mfma_f64_16x16x4_f64 with an on-device-probed fragment layout.
// Rounds 6-10 evidence: every gemm structure converges to MfmaUtil ~2/3 and
// ~51 TF sustained -> hypothesis: f64 MFMA pipe occupancy is ~96 cyc (peak
// ~52.4 TF dense), not the 64-cyc/78.6 TF the derived counter assumes.
// k_fpeak µbench (128 MFMA/wave, no memory) decides: ~10.2µs = 96cyc,
// ~6.8µs = 64cyc. Gemm: R8's j=64/wave 1-wave-block structure + t-split
// (blockIdx.z = 32-t half) so C1=C2=16 -> P=32MB -> reduce traffic halved.
// ---------------------------------------------------------------------------

__global__ __launch_bounds__(64) void k_fpeak(double* __restrict__ out)
{
    double a = (double)(threadIdx.x & 63) * 1e-6;
    double b = 1.0 + (double)blockIdx.x * 1e-9;
    d4 c0 = {0,0,0,0}, c1 = {0,0,0,0}, c2 = {0,0,0,0}, c3 = {0,0,0,0};
#pragma unroll
    for (int r = 0; r < 32; ++r) {   // 128 independent-chain MFMAs
        c0 = __builtin_amdgcn_mfma_f64_16x16x4f64(a, b, c0, 0, 0, 0);
        c1 = __builtin_amdgcn_mfma_f64_16x16x4f64(a, b, c1, 0, 0, 0);
        c2 = __builtin_amdgcn_mfma_f64_16x16x4f64(a, b, c2, 0, 0, 0);
        c3 = __builtin_amdgcn_mfma_f64_16x16x4f64(a, b, c3, 0, 0, 0);
    }
    out[(size_t)blockIdx.x * 64 + threadIdx.x] = c0[0] + c1[1] + c2[2] + c3[3];
}

__global__ __launch_bounds__(64) void k_probe(int* __restrict__ lut)
{
    int l = threadIdx.x;
    d4 z = {0.0, 0.0, 0.0, 0.0};
    d4 d1 = __builtin_amdgcn_mfma_f64_16x16x4f64(1.0, (double)l, z, 0, 0, 0);
    d4 d2 = __builtin_amdgcn_mfma_f64_16x16x4f64((double)l, 1.0, z, 0, 0, 0);
    int amode = 0, bmode = 0;
    int rw[4], cl[4];
#pragma unroll
    for (int r = 0; r < 4; ++r) {
        int v1 = (int)(d1[r] + 0.5);
        if ((v1 & 3) == 0) { cl[r] = (v1 - 96) >> 2; bmode = 0; }
        else               { cl[r] = (v1 - 6) >> 4;  bmode = 1; }
        int v2 = (int)(d2[r] + 0.5);
        if ((v2 & 3) == 0) { rw[r] = (v2 - 96) >> 2; amode = 0; }
        else               { rw[r] = (v2 - 6) >> 4;  amode = 1; }
    }
    {
        int m = l >> 2, k = l & 3;
        lut[l] = (amode == 0) ? (m + (k << 4)) : ((m << 2) + k);
    }
    lut[64 + l]  = (bmode == 0) ? (l >> 4) : (l & 3);
    lut[128 + l] = (bmode == 0) ? (l & 15) : (l >> 2);
#pragma unroll
    for (int r = 0; r < 4; ++r) {
        lut[192 + (r << 6) + l] = rw[r];
        lut[448 + (r << 6) + l] = cl[r];
    }
}

// SA block layout: SA[i>>2][tt=t>>4][ lane = lutAinv[(t&15)*4 + (i&3)] ]
__global__ __launch_bounds__(256) void k_input(const float* __restrict__ img,
                                               float* __restrict__ out0, // 65 x n
                                               double* __restrict__ SA0,
                                               const int* __restrict__ lut, int n)
{
    int i = blockIdx.x * 256 + threadIdx.x;
    if (i >= n) return;
    int lanes[16];
#pragma unroll
    for (int m = 0; m < 16; ++m) lanes[m] = lut[(m << 2) + (i & 3)];
    double* base = SA0 + ((size_t)(i >> 2) << 8);
    double m = 0.0;
    double x = (double)img[i];
#pragma unroll
    for (int t = 0; t < 64; ++t) {
        m += x;
        bool fire = (m >= 1.0);
        if (fire) m -= 1.0;          // input layer: no decay
        out0[(size_t)t * n + i] = fire ? 1.0f : 0.0f;
        base[((t >> 4) << 6) + lanes[t & 15]] = fire ? 1.0 : 0.0;
    }
    out0[(size_t)64 * n + i] = 0.0f; // pad_tail: last row zero
}

// MFMA spike-gated GEMM partials: P[c][t][j] = sum_{i in chunk c} S[t][i]*W[i][j]
// Grid: (n_out/64, nchunks, 2). Block = 1 wave; wave owns 64 j x 32 t (t-half
// = blockIdx.z). Depth-2 pipeline, 3 SSA register sets; 8 MFMA + 6 loads/step.
__global__ __launch_bounds__(64) void k_gemm(const float* __restrict__ W,
                                             const double* __restrict__ SA,
                                             double* __restrict__ P,
                                             const int* __restrict__ lut,
                                             int n_in, int n_out, int i_per_chunk)
{
    const int lane = threadIdx.x & 63;
    const int j0   = blockIdx.x * 64;
    const int c    = blockIdx.y;
    const int th   = blockIdx.z;          // 0: t 0..31, 1: t 32..63

    const int kB = lut[64 + lane];
    const int nB = lut[128 + lane];
    int rw[4], cl[4];
#pragma unroll
    for (int r = 0; r < 4; ++r) {
        rw[r] = lut[192 + (r << 6) + lane];
        cl[r] = lut[448 + (r << 6) + lane];
    }

    int i0 = c * i_per_chunk;
    int i1 = i0 + i_per_chunk; if (i1 > n_in) i1 = n_in;
    int nsteps = (i1 > i0) ? ((i1 - i0) >> 2) : 0;   // 4 i's per step

    d4 acc[4][2];   // [jt][ttl]
#pragma unroll
    for (int jt = 0; jt < 4; ++jt)
#pragma unroll
        for (int tl = 0; tl < 2; ++tl) acc[jt][tl] = (d4){0.0, 0.0, 0.0, 0.0};

    const size_t wstep = (size_t)4 * n_out;          // W elems per step
    const float*  wp0 = W  + (size_t)(i0 + kB) * n_out + j0 + nB;
    const double* ap0 = SA + (((size_t)i0 >> 2) << 8) + (th << 7) + lane;

    // three load sets, each serving steps s = k, k+3, k+6, ...
    const float*  Awp = wp0;              const double* Aap = ap0;
    const float*  Bwp = wp0 + wstep;      const double* Bap = ap0 + 256;
    const float*  Cwp = wp0 + 2 * wstep;  const double* Cap = ap0 + 512;
    double Aa0, Aa1; float Ab0, Ab1, Ab2, Ab3;
    double Ba0, Ba1; float Bb0, Bb1, Bb2, Bb3;
    double Ca0, Ca1; float Cb0, Cb1, Cb2, Cb3;

#define LOADSET(S, sidx) do {                                                  \
        if ((sidx) < nsteps) {                                                 \
            S##b0 = S##wp[0];  S##b1 = S##wp[16];                              \
            S##b2 = S##wp[32]; S##b3 = S##wp[48];                              \
            S##a0 = S##ap[0];  S##a1 = S##ap[64];                              \
        } else {                                                               \
            S##b0 = 0.f; S##b1 = 0.f; S##b2 = 0.f; S##b3 = 0.f;                \
            S##a0 = 0.0; S##a1 = 0.0;                                          \
        }                                                                      \
        S##wp += 3 * wstep; S##ap += 768;                                      \
    } while (0)

#define COMPUTESET(S) do {                                                     \
        double b;                                                              \
        b = (double)S##b0;                                                     \
        acc[0][0] = __builtin_amdgcn_mfma_f64_16x16x4f64(S##a0, b, acc[0][0], 0, 0, 0); \
        acc[0][1] = __builtin_amdgcn_mfma_f64_16x16x4f64(S##a1, b, acc[0][1], 0, 0, 0); \
        b = (double)S##b1;                                                     \
        acc[1][0] = __builtin_amdgcn_mfma_f64_16x16x4f64(S##a0, b, acc[1][0], 0, 0, 0); \
        acc[1][1] = __builtin_amdgcn_mfma_f64_16x16x4f64(S##a1, b, acc[1][1], 0, 0, 0); \
        b = (double)S##b2;                                                     \
        acc[2][0] = __builtin_amdgcn_mfma_f64_16x16x4f64(S##a0, b, acc[2][0], 0, 0, 0); \
        acc[2][1] = __builtin_amdgcn_mfma_f64_16x16x4f64(S##a1, b, acc[2][1], 0, 0, 0); \
        b = (double)S##b3;                                                     \
        acc[3][0] = __builtin_amdgcn_mfma_f64_16x16x4f64(S##a0, b, acc[3][0], 0, 0, 0); \
        acc[3][1] = __builtin_amdgcn_mfma_f64_16x16x4f64(S##a1, b, acc[3][1], 0, 0, 0); \
    } while (0)

    LOADSET(A, 0);
    LOADSET(B, 1);
    LOADSET(C, 2);

    int rounds = (nsteps + 2) / 3;
    int s = 0;
    for (int r = 0; r < rounds; ++r) {
        COMPUTESET(A); LOADSET(A, s + 3);   // consumed 2 compute-steps later
        COMPUTESET(B); LOADSET(B, s + 4);
        COMPUTESET(C); LOADSET(C, s + 5);
        s += 3;
    }
#undef LOADSET
#undef COMPUTESET

    // D element (lane, r) of tile (jt, ttl) -> row (th*2+ttl)*16+rw[r], col j0+jt*16+cl[r]
    double* pc = P + (size_t)c * 64 * n_out;
#pragma unroll
    for (int jt = 0; jt < 4; ++jt)
#pragma unroll
        for (int tl = 0; tl < 2; ++tl)
#pragma unroll
            for (int r = 0; r < 4; ++r)
                pc[(size_t)(((th * 2 + tl) * 16) + rw[r]) * n_out + (j0 + jt * 16 + cl[r])] = acc[jt][tl][r];
}

// U[t][j] = sum over chunks c of P[c][t][j]  (fixed order: deterministic)
__global__ __launch_bounds__(256) void k_reduceU(const double* __restrict__ P,
                                                 double* __restrict__ U,
                                                 int nchunks, int n_out)
{
    int gid = blockIdx.x * 256 + threadIdx.x;
    int total = 64 * n_out;
    if (gid >= total) return;
    int t = gid / n_out;
    int j = gid - t * n_out;
    double s = 0.0;
    for (int c = 0; c < nchunks; ++c)
        s += P[((size_t)c * 64 + t) * n_out + j];
    U[gid] = s;
}

// Per-neuron membrane scan; emits next layer's spike fragments via the LUT.
// shift=1 => this layer consumes the previous step's spikes (read U[t-1]).
__global__ __launch_bounds__(256) void k_scan(const double* __restrict__ U,
                                              float* __restrict__ outS, // 65 x n_out (pad_head)
                                              double* __restrict__ SAn, // may be null
                                              const int* __restrict__ lut,
                                              int n_out, int shift)
{
    int j = blockIdx.x * 256 + threadIdx.x;
    if (j >= n_out) return;
    int lanes[16];
#pragma unroll
    for (int m = 0; m < 16; ++m) lanes[m] = lut[(m << 2) + (j & 3)];
    double* base = SAn ? (SAn + ((size_t)(j >> 2) << 8)) : (double*)nullptr;
    double m = 0.0;
    outS[j] = 0.0f;                           // row 0 zero (pad_head)
#pragma unroll
    for (int t = 0; t < 64; ++t) {
        int s = t - shift;
        double u = (s >= 0) ? U[(size_t)s * n_out + j] : 0.0;
        m += u;
        bool fire = (m >= 1.0);
        m = fire ? (m - 1.0) : (m * 0.5);
        outS[(size_t)(t + 1) * n_out + j] = fire ? 1.0f : 0.0f;
        if (base) base[((t >> 4) << 6) + lanes[t & 15]] = fire ? 1.0 : 0.0;
    }
}

extern "C" void kernel_launch(void* const* d_in, const int* in_sizes, int n_in_cnt,
                              void* d_out, int out_size, void* d_ws, size_t ws_size,
                              hipStream_t stream)
{
    const float* img = (const float*)d_in[0];
    const float* w1  = (const float*)d_in[1];
    const float* w2  = (const float*)d_in[2];
    const float* w3  = (const float*)d_in[3];

    const int N0 = 16384, N1 = 4096, N2 = 4096, N3 = 1024;

    float* out0 = (float*)d_out;
    float* out1 = out0 + (size_t)65 * N0;
    float* out2 = out1 + (size_t)65 * N1;
    float* out3 = out2 + (size_t)65 * N2;

    // workspace layout
    char* ws = (char*)d_ws;
    const size_t MB = 1024 * 1024;
    double* SA0 = (double*)(ws);               // 16384*64*8 = 8 MiB
    double* SA1 = (double*)(ws + 8 * MB);      //  2 MiB
    double* SA2 = (double*)(ws + 10 * MB);     //  2 MiB
    double* U   = (double*)(ws + 12 * MB);     //  2 MiB
    int*    lut = (int*)   (ws + 14 * MB);     //  2816 B (704 ints)
    double* P   = (double*)(ws + 14 * MB + 4096);   // also k_fpeak scratch (1MB, pre-gemm)

    size_t fixed = 14 * MB + 4096;
    size_t pbudget = (ws_size > fixed) ? (ws_size - fixed) : 0;

    // P bytes per chunk = 64 t x n_out x 8B = 512*n_out
    auto clampi = [](long v, int lo, int hi) { int x = (int)v; if (x < lo) x = lo; if (x > hi) x = hi; return x; };
    int C1 = clampi((long)(pbudget / (512ull * N1)), 1, 16);  // 64x16x2 = 2048 blocks
    int C2 = clampi((long)(pbudget / (512ull * N2)), 1, 16);
    int C3 = clampi((long)(pbudget / (512ull * N3)), 1, 64);  // 16x64x2 = 2048 blocks

    auto ipc4 = [](int n_in, int C) { return (((n_in + C - 1) / C) + 3) & ~3; };

    // f64 MFMA peak µbench: 2048 blocks x 128 MFMA, no memory in loop.
    // dur ~10.2µs -> 96 cyc/MFMA (52.4 TF peak); ~6.8µs -> 64 cyc (78.6 TF).
    k_fpeak<<<2048, 64, 0, stream>>>(P);

    // measure the f64 MFMA fragment layout (writes lut; same stream -> ordered)
    k_probe<<<1, 64, 0, stream>>>(lut);

    // layer 0 (input): spikes + fragment-layout S0
    k_input<<<N0 / 256, 256, 0, stream>>>(img, out0, SA0, lut, N0);

    // layer 1: U1 = S0 @ W1 (same-step spikes)
    k_gemm<<<dim3(N1 / 64, C1, 2), 64, 0, stream>>>(w1, SA0, P, lut, N0, N1, ipc4(N0, C1));
    k_reduceU<<<(64 * N1) / 256, 256, 0, stream>>>(P, U, C1, N1);
    k_scan<<<N1 / 256, 256, 0, stream>>>(U, out1, SA1, lut, N1, 0);

    // layer 2: uses previous-step s1
    k_gemm<<<dim3(N2 / 64, C2, 2), 64, 0, stream>>>(w2, SA1, P, lut, N1, N2, ipc4(N1, C2));
    k_reduceU<<<(64 * N2) / 256, 256, 0, stream>>>(P, U, C2, N2);
    k_scan<<<N2 / 256, 256, 0, stream>>>(U, out2, SA2, lut, N2, 1);

    // layer 3: uses previous-step s2
    k_gemm<<<dim3(N3 / 64, C3, 2), 64, 0, stream>>>(w3, SA2, P, lut, N1, N3, ipc4(N1, C3));
    k_reduceU<<<(64 * N3) / 256, 256, 0, stream>>>(P, U, C3, N3);
    k_scan<<<N3 / 256, 256, 0, stream>>>(U, out3, (double*)nullptr, lut, N3, 1);
}

// Round 12
// 241.496 us; speedup vs baseline: 1.6460x; 1.4440x over previous
//
#include <hip/hip_runtime.h>
#include <cstdint>

typedef float f4 __attribute__((ext_vector_type(4)));
typedef short bf8 __attribute__((ext_vector_type(8)));
typedef unsigned int u32;
typedef unsigned int u32x4 __attribute__((ext_vector_type(4)));
typedef unsigned short u16;

// ---------------------------------------------------------------------------
// SNN: 64-step scan over 3 spike-gated linear layers.
// Rounds 6-11: f64 MFMA path converges to ~51 TF at every structure ->
// v_mfma_f64_16x16x4 pipe occupancy ~96 cyc; layer-1 floor 164 µs (measured
// 171 = 96%). Round-12: switch GEMM to EXACT-SPLIT bf16x3:
//   w(f32) = hi + mid + lo, each bf16 by TRUNCATION (3x8 mantissa bits = 24
//   = f32 mantissa; bf16 exponent range == f32 -> split exact, zero error).
//   U = S*Whi + S*Wmid + S*Wlo via mfma_f32_16x16x32_bf16, 3 planes chained
//   into one f32 acc, flushed to f64 every K=32 (f32 noise ~2e-7 rms vs
//   fire margins ~1e-5). Spikes exact 0/1 bf16. Layer-1 becomes HBM-bound.
// Probe-LUT (proven in f64 rounds) redone for bf16 C/D + lane modes;
// k-pairing needs no probe (any bijection works if A/B share it).
// ---------------------------------------------------------------------------

__device__ __forceinline__ float uf(u32 x) { return __builtin_bit_cast(float, x); }
__device__ __forceinline__ u32 fu(float x) { return __builtin_bit_cast(u32, x); }

// LUT: [0..63] writer lane for (m=idx>>2, g=idx&3); [64..127] gB; [128..191] nB;
// [192..447] rwD[r*64+lane]; [448..703] clD[r*64+lane]
__global__ __launch_bounds__(64) void k_probe(int* __restrict__ lut)
{
    int l = threadIdx.x;
    u32 lb = fu((float)l) >> 16;            // bf16 bits of lane id (exact, l<=63)
    u32 lbb = lb | (lb << 16);
    u32x4 lv4 = {lbb, lbb, lbb, lbb};
    u32x4 on4 = {0x3F803F80u, 0x3F803F80u, 0x3F803F80u, 0x3F803F80u};
    bf8 lv = __builtin_bit_cast(bf8, lv4);
    bf8 on = __builtin_bit_cast(bf8, on4);
    f4 z = {0.f, 0.f, 0.f, 0.f};
    // d1[m][n] = sum_k B[k][n] : col fingerprint; d2: row fingerprint.
    // mode0 (n=lane&15): 8*(4n+96)=32n+768; mode1 (n=lane>>2): 8*(16n+6)=128n+48
    f4 d1 = __builtin_amdgcn_mfma_f32_16x16x32_bf16(on, lv, z, 0, 0, 0);
    f4 d2 = __builtin_amdgcn_mfma_f32_16x16x32_bf16(lv, on, z, 0, 0, 0);
    int amode = 0, bmode = 0;
    int rw[4], cl[4];
#pragma unroll
    for (int r = 0; r < 4; ++r) {
        int v1 = (int)(d1[r] + 0.5f);
        if (v1 >= 768 && v1 <= 1248 && ((v1 - 768) & 31) == 0) { cl[r] = (v1 - 768) >> 5; bmode = 0; }
        else                                                   { cl[r] = (v1 - 48) >> 7;  bmode = 1; }
        int v2 = (int)(d2[r] + 0.5f);
        if (v2 >= 768 && v2 <= 1248 && ((v2 - 768) & 31) == 0) { rw[r] = (v2 - 768) >> 5; amode = 0; }
        else                                                   { rw[r] = (v2 - 48) >> 7;  amode = 1; }
    }
    {
        int m = l >> 2, g = l & 3;
        lut[l] = (amode == 0) ? (g * 16 + m) : (m * 4 + g);
    }
    lut[64 + l]  = (bmode == 0) ? (l >> 4) : (l & 3);
    lut[128 + l] = (bmode == 0) ? (l & 15) : (l >> 2);
#pragma unroll
    for (int r = 0; r < 4; ++r) {
        lut[192 + (r << 6) + l] = rw[r];
        lut[448 + (r << 6) + l] = cl[r];
    }
}

// Spike fragment store: SA[i>>5][tt=t>>4][lane][e]; writer lane from LUT,
// e = i&7, spike for (t, i_local = g*8 + e) with g = (i&31)>>3.
__global__ __launch_bounds__(256) void k_input(const float* __restrict__ img,
                                               float* __restrict__ out0, // 65 x n
                                               u16* __restrict__ SA0,
                                               const int* __restrict__ lut, int n)
{
    int i = blockIdx.x * 256 + threadIdx.x;
    if (i >= n) return;
    int g = (i & 31) >> 3, e = i & 7;
    int lanes[16];
#pragma unroll
    for (int m = 0; m < 16; ++m) lanes[m] = lut[(m << 2) + g];
    u16* base = SA0 + ((size_t)(i >> 5)) * 2048 + e;
    double m = 0.0;
    double x = (double)img[i];
#pragma unroll
    for (int t = 0; t < 64; ++t) {
        m += x;
        bool fire = (m >= 1.0);
        if (fire) m -= 1.0;          // input layer: no decay
        out0[(size_t)t * n + i] = fire ? 1.0f : 0.0f;
        base[((t >> 4) << 9) + (lanes[t & 15] << 3)] = fire ? (u16)0x3F80 : (u16)0;
    }
    out0[(size_t)64 * n + i] = 0.0f; // pad_tail: last row zero
}

// split 2 f32 (even,odd) -> packed bf16 dwords for hi/mid/lo planes (exact)
#define SPLIT2(we, wo, hD, mD, lD) do {                                        \
    u32 he = (we) & 0xFFFF0000u; float r1e = uf(we) - uf(he);                  \
    u32 me = fu(r1e) & 0xFFFF0000u; float r2e = r1e - uf(me); u32 le = fu(r2e);\
    u32 ho = (wo) & 0xFFFF0000u; float r1o = uf(wo) - uf(ho);                  \
    u32 mo = fu(r1o) & 0xFFFF0000u; float r2o = r1o - uf(mo); u32 lo2 = fu(r2o);\
    hD = (he >> 16) | ho; mD = (me >> 16) | mo;                                \
    lD = (le >> 16) | (lo2 & 0xFFFF0000u);                                     \
} while (0)

// bf16x3 spike-gated GEMM partials: P[c][t][j] = sum_{i in chunk} S[t][i]W[i][j]
// Grid (n_out/16, C); 1-wave blocks; wave owns 16 j x 64 t; K-step = 32.
template<int NOUT>
__global__ __launch_bounds__(64, 3) void k_gemm(const float* __restrict__ W,
                                                const u16* __restrict__ SA,
                                                double* __restrict__ P,
                                                const int* __restrict__ lut,
                                                int n_in, int ipc)
{
    const int lane = threadIdx.x;
    const int j0   = blockIdx.x * 16;
    const int c    = blockIdx.y;
    const int gB   = lut[64 + lane];
    const int nB   = lut[128 + lane];
    int rw[4], cl[4];
#pragma unroll
    for (int r = 0; r < 4; ++r) {
        rw[r] = lut[192 + (r << 6) + lane];
        cl[r] = lut[448 + (r << 6) + lane];
    }

    int i0 = c * ipc;
    int i1 = i0 + ipc; if (i1 > n_in) i1 = n_in;
    int nsteps = (i1 > i0) ? ((i1 - i0) >> 5) : 0;   // 32 i's per step

    double accd[4][4];
#pragma unroll
    for (int tt = 0; tt < 4; ++tt)
#pragma unroll
        for (int r = 0; r < 4; ++r) accd[tt][r] = 0.0;

    const u32* wp0 = (const u32*)(W + (size_t)(i0 + gB * 8) * NOUT + j0 + nB);
    const u16* ap0 = SA + (size_t)(i0 >> 5) * 2048 + lane * 8;
    const size_t wstep = (size_t)32 * NOUT;

    const u32* Awp = wp0;              const u16* Aap = ap0;
    const u32* Bwp = wp0 + wstep;      const u16* Bap = ap0 + 2048;
    const u32* Cwp = wp0 + 2 * wstep;  const u16* Cap = ap0 + 4096;
    u32 Aw0,Aw1,Aw2,Aw3,Aw4,Aw5,Aw6,Aw7; u32x4 Aa0,Aa1,Aa2,Aa3;
    u32 Bw0,Bw1,Bw2,Bw3,Bw4,Bw5,Bw6,Bw7; u32x4 Ba0,Ba1,Ba2,Ba3;
    u32 Cw0,Cw1,Cw2,Cw3,Cw4,Cw5,Cw6,Cw7; u32x4 Ca0,Ca1,Ca2,Ca3;

#define LOADSET(S, sidx) do {                                                  \
        if ((sidx) < nsteps) {                                                 \
            S##w0 = S##wp[0];        S##w1 = S##wp[(size_t)NOUT];              \
            S##w2 = S##wp[2*(size_t)NOUT]; S##w3 = S##wp[3*(size_t)NOUT];      \
            S##w4 = S##wp[4*(size_t)NOUT]; S##w5 = S##wp[5*(size_t)NOUT];      \
            S##w6 = S##wp[6*(size_t)NOUT]; S##w7 = S##wp[7*(size_t)NOUT];      \
            S##a0 = *(const u32x4*)(S##ap);                                    \
            S##a1 = *(const u32x4*)(S##ap + 512);                              \
            S##a2 = *(const u32x4*)(S##ap + 1024);                             \
            S##a3 = *(const u32x4*)(S##ap + 1536);                             \
        } else {                                                               \
            S##w0=0;S##w1=0;S##w2=0;S##w3=0;S##w4=0;S##w5=0;S##w6=0;S##w7=0;   \
            S##a0 = (u32x4){0,0,0,0}; S##a1 = (u32x4){0,0,0,0};                \
            S##a2 = (u32x4){0,0,0,0}; S##a3 = (u32x4){0,0,0,0};                \
        }                                                                      \
        S##wp += 3 * wstep; S##ap += 6144;                                     \
    } while (0)

#define COMPUTESET(S) do {                                                     \
        u32 hd0,hd1,hd2,hd3, md0,md1,md2,md3, ld0,ld1,ld2,ld3;                 \
        SPLIT2(S##w0, S##w1, hd0, md0, ld0);                                   \
        SPLIT2(S##w2, S##w3, hd1, md1, ld1);                                   \
        SPLIT2(S##w4, S##w5, hd2, md2, ld2);                                   \
        SPLIT2(S##w6, S##w7, hd3, md3, ld3);                                   \
        u32x4 hv = {hd0,hd1,hd2,hd3}, mv = {md0,md1,md2,md3},                  \
              lv2 = {ld0,ld1,ld2,ld3};                                         \
        bf8 Bh = __builtin_bit_cast(bf8, hv);                                  \
        bf8 Bm = __builtin_bit_cast(bf8, mv);                                  \
        bf8 Bl = __builtin_bit_cast(bf8, lv2);                                 \
        f4 zz = {0.f,0.f,0.f,0.f};                                             \
        {                                                                      \
            bf8 Af = __builtin_bit_cast(bf8, S##a0);                           \
            f4 acc = __builtin_amdgcn_mfma_f32_16x16x32_bf16(Af, Bh, zz, 0,0,0); \
            acc = __builtin_amdgcn_mfma_f32_16x16x32_bf16(Af, Bm, acc, 0,0,0); \
            acc = __builtin_amdgcn_mfma_f32_16x16x32_bf16(Af, Bl, acc, 0,0,0); \
            accd[0][0] += (double)acc[0]; accd[0][1] += (double)acc[1];        \
            accd[0][2] += (double)acc[2]; accd[0][3] += (double)acc[3];        \
        }                                                                      \
        {                                                                      \
            bf8 Af = __builtin_bit_cast(bf8, S##a1);                           \
            f4 acc = __builtin_amdgcn_mfma_f32_16x16x32_bf16(Af, Bh, zz, 0,0,0); \
            acc = __builtin_amdgcn_mfma_f32_16x16x32_bf16(Af, Bm, acc, 0,0,0); \
            acc = __builtin_amdgcn_mfma_f32_16x16x32_bf16(Af, Bl, acc, 0,0,0); \
            accd[1][0] += (double)acc[0]; accd[1][1] += (double)acc[1];        \
            accd[1][2] += (double)acc[2]; accd[1][3] += (double)acc[3];        \
        }                                                                      \
        {                                                                      \
            bf8 Af = __builtin_bit_cast(bf8, S##a2);                           \
            f4 acc = __builtin_amdgcn_mfma_f32_16x16x32_bf16(Af, Bh, zz, 0,0,0); \
            acc = __builtin_amdgcn_mfma_f32_16x16x32_bf16(Af, Bm, acc, 0,0,0); \
            acc = __builtin_amdgcn_mfma_f32_16x16x32_bf16(Af, Bl, acc, 0,0,0); \
            accd[2][0] += (double)acc[0]; accd[2][1] += (double)acc[1];        \
            accd[2][2] += (double)acc[2]; accd[2][3] += (double)acc[3];        \
        }                                                                      \
        {                                                                      \
            bf8 Af = __builtin_bit_cast(bf8, S##a3);                           \
            f4 acc = __builtin_amdgcn_mfma_f32_16x16x32_bf16(Af, Bh, zz, 0,0,0); \
            acc = __builtin_amdgcn_mfma_f32_16x16x32_bf16(Af, Bm, acc, 0,0,0); \
            acc = __builtin_amdgcn_mfma_f32_16x16x32_bf16(Af, Bl, acc, 0,0,0); \
            accd[3][0] += (double)acc[0]; accd[3][1] += (double)acc[1];        \
            accd[3][2] += (double)acc[2]; accd[3][3] += (double)acc[3];        \
        }                                                                      \
    } while (0)

    LOADSET(A, 0);
    LOADSET(B, 1);
    LOADSET(C, 2);

    int rounds = (nsteps + 2) / 3;
    int s = 0;
    for (int r = 0; r < rounds; ++r) {
        COMPUTESET(A); LOADSET(A, s + 3);
        COMPUTESET(B); LOADSET(B, s + 4);
        COMPUTESET(C); LOADSET(C, s + 5);
        s += 3;
    }
#undef LOADSET
#undef COMPUTESET

    double* pc = P + (size_t)c * 64 * NOUT;
#pragma unroll
    for (int tt = 0; tt < 4; ++tt)
#pragma unroll
        for (int r = 0; r < 4; ++r)
            pc[(size_t)(tt * 16 + rw[r]) * NOUT + (j0 + cl[r])] = accd[tt][r];
}

// U[t][j] = sum over chunks c of P[c][t][j]  (fixed order: deterministic)
__global__ __launch_bounds__(256) void k_reduceU(const double* __restrict__ P,
                                                 double* __restrict__ U,
                                                 int nchunks, int n_out)
{
    int gid = blockIdx.x * 256 + threadIdx.x;
    int total = 64 * n_out;
    if (gid >= total) return;
    int t = gid / n_out;
    int j = gid - t * n_out;
    double s = 0.0;
    for (int c = 0; c < nchunks; ++c)
        s += P[((size_t)c * 64 + t) * n_out + j];
    U[gid] = s;
}

// Per-neuron membrane scan; emits next layer's bf16 spike fragments.
__global__ __launch_bounds__(256) void k_scan(const double* __restrict__ U,
                                              float* __restrict__ outS, // 65 x n_out
                                              u16* __restrict__ SAn,    // may be null
                                              const int* __restrict__ lut,
                                              int n_out, int shift)
{
    int j = blockIdx.x * 256 + threadIdx.x;
    if (j >= n_out) return;
    int g = (j & 31) >> 3, e = j & 7;
    int lanes[16];
#pragma unroll
    for (int m = 0; m < 16; ++m) lanes[m] = lut[(m << 2) + g];
    u16* base = SAn ? (SAn + ((size_t)(j >> 5)) * 2048 + e) : (u16*)nullptr;
    double m = 0.0;
    outS[j] = 0.0f;                           // row 0 zero (pad_head)
#pragma unroll
    for (int t = 0; t < 64; ++t) {
        int s = t - shift;
        double u = (s >= 0) ? U[(size_t)s * n_out + j] : 0.0;
        m += u;
        bool fire = (m >= 1.0);
        m = fire ? (m - 1.0) : (m * 0.5);
        outS[(size_t)(t + 1) * n_out + j] = fire ? 1.0f : 0.0f;
        if (base) base[((t >> 4) << 9) + (lanes[t & 15] << 3)] = fire ? (u16)0x3F80 : (u16)0;
    }
}

extern "C" void kernel_launch(void* const* d_in, const int* in_sizes, int n_in_cnt,
                              void* d_out, int out_size, void* d_ws, size_t ws_size,
                              hipStream_t stream)
{
    const float* img = (const float*)d_in[0];
    const float* w1  = (const float*)d_in[1];
    const float* w2  = (const float*)d_in[2];
    const float* w3  = (const float*)d_in[3];

    const int N0 = 16384, N1 = 4096, N2 = 4096, N3 = 1024;

    float* out0 = (float*)d_out;
    float* out1 = out0 + (size_t)65 * N0;
    float* out2 = out1 + (size_t)65 * N1;
    float* out3 = out2 + (size_t)65 * N2;

    // workspace layout
    char* ws = (char*)d_ws;
    const size_t MB = 1024 * 1024;
    u16*    SA0 = (u16*)(ws);                     // 16384*64*2 = 2 MiB
    u16*    SA1 = (u16*)(ws + 2 * MB);            // 512 KiB
    u16*    SA2 = (u16*)(ws + 2 * MB + 512 * 1024);
    double* U   = (double*)(ws + 3 * MB);         // 2 MiB
    int*    lut = (int*)  (ws + 5 * MB);          // 2816 B
    double* P   = (double*)(ws + 5 * MB + 4096);

    size_t fixed = 5 * MB + 4096;
    size_t pbudget = (ws_size > fixed) ? (ws_size - fixed) : 0;

    auto clampi = [](long v, int lo, int hi) { int x = (int)v; if (x < lo) x = lo; if (x > hi) x = hi; return x; };
    int C1 = clampi((long)(pbudget / (512ull * N1)), 1, 16);
    int C2 = clampi((long)(pbudget / (512ull * N2)), 1, 8);
    int C3 = clampi((long)(pbudget / (512ull * N3)), 1, 32);

    auto ipc32 = [](int n_in, int C) { return (((n_in + C - 1) / C) + 31) & ~31; };

    // measure bf16 MFMA C/D layout + lane modes (same stream -> ordered)
    k_probe<<<1, 64, 0, stream>>>(lut);

    // layer 0 (input): spikes + bf16 fragment-layout S0
    k_input<<<N0 / 256, 256, 0, stream>>>(img, out0, SA0, lut, N0);

    // layer 1: U1 = S0 @ W1 (same-step spikes)
    k_gemm<4096><<<dim3(N1 / 16, C1), 64, 0, stream>>>(w1, SA0, P, lut, N0, ipc32(N0, C1));
    k_reduceU<<<(64 * N1) / 256, 256, 0, stream>>>(P, U, C1, N1);
    k_scan<<<N1 / 256, 256, 0, stream>>>(U, out1, SA1, lut, N1, 0);

    // layer 2: uses previous-step s1
    k_gemm<4096><<<dim3(N2 / 16, C2), 64, 0, stream>>>(w2, SA1, P, lut, N1, ipc32(N1, C2));
    k_reduceU<<<(64 * N2) / 256, 256, 0, stream>>>(P, U, C2, N2);
    k_scan<<<N2 / 256, 256, 0, stream>>>(U, out2, SA2, lut, N2, 1);

    // layer 3: uses previous-step s2
    k_gemm<1024><<<dim3(N3 / 16, C3), 64, 0, stream>>>(w3, SA2, P, lut, N2, ipc32(N2, C3));
    k_reduceU<<<(64 * N3) / 256, 256, 0, stream>>>(P, U, C3, N3);
    k_scan<<<N3 / 256, 256, 0, stream>>>(U, out3, (u16*)nullptr, lut, N3, 1);
}

// Round 13
// 218.233 us; speedup vs baseline: 1.8215x; 1.1066x over previous
//
#include <hip/hip_runtime.h>
#include <cstdint>

typedef float f4 __attribute__((ext_vector_type(4)));
typedef short bf8 __attribute__((ext_vector_type(8)));
typedef unsigned int u32;
typedef unsigned int u32x4 __attribute__((ext_vector_type(4)));
typedef unsigned short u16;

// ---------------------------------------------------------------------------
// SNN: 64-step scan over 3 spike-gated linear layers.
// GEMM: EXACT-SPLIT bf16x3 (w = hi+mid+lo by truncation; 3x8 mantissa bits
// = f32's 24, bf16 exponent = f32 -> exact). 3 planes chained in one f32 MFMA
// acc, flushed to f64 every K=32. Spikes exact 0/1 bf16. absmax 0 (R12).
// R13 changes: (1) j=32/wave (2 B-frags, 16 cols apart) so each wave touches
// both 64B halves of every 128B weight line -> kills potential granule waste,
// halves A-fragment L2 re-reads; (2) layout probe inlined (2 MFMAs/block,
// removes k_probe dispatch + lut traffic); (3) C3 32->16 (P traffic down).
// ---------------------------------------------------------------------------

__device__ __forceinline__ float uf(u32 x) { return __builtin_bit_cast(float, x); }
__device__ __forceinline__ u32 fu(float x) { return __builtin_bit_cast(u32, x); }

struct FragMap { int amode, bmode, rw[4], cl[4]; };

// Inline layout probe: 2 MFMAs with ones/lane-id operands decode the C/D
// coords (rw/cl per reg) and the A/B lane modes. Proven decode (R12).
// d1[m][n] = 8*sum_k B[k][n]: mode0 (n=lane&15) -> 32n+768; mode1 -> 128n+48.
__device__ __forceinline__ FragMap probe_map()
{
    int l = threadIdx.x & 63;
    u32 lb = fu((float)l) >> 16;            // exact bf16 of lane id (l<=63)
    u32 lbb = lb | (lb << 16);
    u32x4 lv4 = {lbb, lbb, lbb, lbb};
    u32x4 on4 = {0x3F803F80u, 0x3F803F80u, 0x3F803F80u, 0x3F803F80u};
    bf8 lv = __builtin_bit_cast(bf8, lv4);
    bf8 on = __builtin_bit_cast(bf8, on4);
    f4 z = {0.f, 0.f, 0.f, 0.f};
    f4 d1 = __builtin_amdgcn_mfma_f32_16x16x32_bf16(on, lv, z, 0, 0, 0);
    f4 d2 = __builtin_amdgcn_mfma_f32_16x16x32_bf16(lv, on, z, 0, 0, 0);
    FragMap fm; fm.amode = 0; fm.bmode = 0;
#pragma unroll
    for (int r = 0; r < 4; ++r) {
        int v1 = (int)(d1[r] + 0.5f);
        if (v1 >= 768 && v1 <= 1248 && ((v1 - 768) & 31) == 0) { fm.cl[r] = (v1 - 768) >> 5; fm.bmode = 0; }
        else                                                   { fm.cl[r] = (v1 - 48) >> 7;  fm.bmode = 1; }
        int v2 = (int)(d2[r] + 0.5f);
        if (v2 >= 768 && v2 <= 1248 && ((v2 - 768) & 31) == 0) { fm.rw[r] = (v2 - 768) >> 5; fm.amode = 0; }
        else                                                   { fm.rw[r] = (v2 - 48) >> 7;  fm.amode = 1; }
    }
    return fm;
}

// Spike fragment store: SA[i>>5][tt=t>>4][lane][e]; writer lane from amode,
// e = i&7, g = (i&31)>>3 -> lane holding A row m=(t&15), k-group g.
__global__ __launch_bounds__(256) void k_input(const float* __restrict__ img,
                                               float* __restrict__ out0, // 65 x n
                                               u16* __restrict__ SA0, int n)
{
    FragMap fm = probe_map();
    int i = blockIdx.x * 256 + threadIdx.x;
    if (i >= n) return;
    int g = (i & 31) >> 3, e = i & 7;
    int lanes[16];
#pragma unroll
    for (int m = 0; m < 16; ++m) lanes[m] = (fm.amode == 0) ? (g * 16 + m) : (m * 4 + g);
    u16* base = SA0 + ((size_t)(i >> 5)) * 2048 + e;
    double m = 0.0;
    double x = (double)img[i];
#pragma unroll
    for (int t = 0; t < 64; ++t) {
        m += x;
        bool fire = (m >= 1.0);
        if (fire) m -= 1.0;          // input layer: no decay
        out0[(size_t)t * n + i] = fire ? 1.0f : 0.0f;
        base[((t >> 4) << 9) + (lanes[t & 15] << 3)] = fire ? (u16)0x3F80 : (u16)0;
    }
    out0[(size_t)64 * n + i] = 0.0f; // pad_tail: last row zero
}

// split 2 f32 (even,odd k) -> packed bf16 dwords for hi/mid/lo planes (exact)
#define SPLIT2(we, wo, hD, mD, lD) do {                                        \
    u32 he = (we) & 0xFFFF0000u; float r1e = uf(we) - uf(he);                  \
    u32 me = fu(r1e) & 0xFFFF0000u; float r2e = r1e - uf(me); u32 le = fu(r2e);\
    u32 ho = (wo) & 0xFFFF0000u; float r1o = uf(wo) - uf(ho);                  \
    u32 mo = fu(r1o) & 0xFFFF0000u; float r2o = r1o - uf(mo); u32 lo2 = fu(r2o);\
    hD = (he >> 16) | ho; mD = (me >> 16) | mo;                                \
    lD = (le >> 16) | (lo2 & 0xFFFF0000u);                                     \
} while (0)

// bf16x3 spike-gated GEMM partials: P[c][t][j] = sum_{i in chunk} S[t][i]W[i][j]
// Grid (n_out/32, C); 1-wave blocks; wave owns 32 j x 64 t; K-step = 32.
// Depth-2 pipeline, 3 SSA load sets; 24 MFMA + 20 loads per step.
template<int NOUT>
__global__ __launch_bounds__(64, 2) void k_gemm(const float* __restrict__ W,
                                                const u16* __restrict__ SA,
                                                double* __restrict__ P,
                                                int n_in, int ipc)
{
    FragMap fm = probe_map();
    const int lane = threadIdx.x;
    const int j0   = blockIdx.x * 32;
    const int c    = blockIdx.y;
    const int gB   = (fm.bmode == 0) ? (lane >> 4) : (lane & 3);
    const int nB   = (fm.bmode == 0) ? (lane & 15) : (lane >> 2);

    int i0 = c * ipc;
    int i1 = i0 + ipc; if (i1 > n_in) i1 = n_in;
    int nsteps = (i1 > i0) ? ((i1 - i0) >> 5) : 0;   // 32 i's per step

    double accd[2][4][4];
#pragma unroll
    for (int jt = 0; jt < 2; ++jt)
#pragma unroll
        for (int tt = 0; tt < 4; ++tt)
#pragma unroll
            for (int r = 0; r < 4; ++r) accd[jt][tt][r] = 0.0;

    const size_t wstep = (size_t)32 * NOUT;
    struct Set { const u32* wp; const u16* ap; u32 w[16]; u32x4 a[4]; };
    Set SA_, SB_, SC_;
    SA_.wp = (const u32*)W + (size_t)(i0 + gB * 8) * NOUT + j0 + nB;
    SB_.wp = SA_.wp + wstep;
    SC_.wp = SA_.wp + 2 * wstep;
    SA_.ap = SA + (size_t)(i0 >> 5) * 2048 + lane * 8;
    SB_.ap = SA_.ap + 2048;
    SC_.ap = SA_.ap + 4096;

#define LOADSET(S, sidx) do {                                                  \
        if ((sidx) < nsteps) {                                                 \
            _Pragma("unroll") for (int k = 0; k < 8; ++k) {                    \
                S.w[k]     = S.wp[(size_t)k * NOUT];                           \
                S.w[8 + k] = S.wp[(size_t)k * NOUT + 16];                      \
            }                                                                  \
            _Pragma("unroll") for (int tt = 0; tt < 4; ++tt)                   \
                S.a[tt] = *(const u32x4*)(S.ap + tt * 512);                    \
        } else {                                                               \
            _Pragma("unroll") for (int k = 0; k < 16; ++k) S.w[k] = 0;         \
            _Pragma("unroll") for (int tt = 0; tt < 4; ++tt)                   \
                S.a[tt] = (u32x4){0, 0, 0, 0};                                 \
        }                                                                      \
        S.wp += 3 * wstep; S.ap += 6144;                                       \
    } while (0)

#define COMPUTESET(S) do {                                                     \
        _Pragma("unroll") for (int jt = 0; jt < 2; ++jt) {                     \
            u32 hd[4], md[4], ld[4];                                           \
            _Pragma("unroll") for (int p = 0; p < 4; ++p)                      \
                SPLIT2(S.w[jt * 8 + 2 * p], S.w[jt * 8 + 2 * p + 1],           \
                       hd[p], md[p], ld[p]);                                   \
            u32x4 hv = {hd[0], hd[1], hd[2], hd[3]};                           \
            u32x4 mv = {md[0], md[1], md[2], md[3]};                           \
            u32x4 lv = {ld[0], ld[1], ld[2], ld[3]};                           \
            bf8 Bh = __builtin_bit_cast(bf8, hv);                              \
            bf8 Bm = __builtin_bit_cast(bf8, mv);                              \
            bf8 Bl = __builtin_bit_cast(bf8, lv);                              \
            f4 zz = {0.f, 0.f, 0.f, 0.f};                                      \
            _Pragma("unroll") for (int tt = 0; tt < 4; ++tt) {                 \
                bf8 Af = __builtin_bit_cast(bf8, S.a[tt]);                     \
                f4 acc = __builtin_amdgcn_mfma_f32_16x16x32_bf16(Af, Bh, zz, 0, 0, 0); \
                acc = __builtin_amdgcn_mfma_f32_16x16x32_bf16(Af, Bm, acc, 0, 0, 0);   \
                acc = __builtin_amdgcn_mfma_f32_16x16x32_bf16(Af, Bl, acc, 0, 0, 0);   \
                _Pragma("unroll") for (int r = 0; r < 4; ++r)                  \
                    accd[jt][tt][r] += (double)acc[r];                         \
            }                                                                  \
        }                                                                      \
    } while (0)

    LOADSET(SA_, 0);
    LOADSET(SB_, 1);
    LOADSET(SC_, 2);

    int rounds = (nsteps + 2) / 3;
    int s = 0;
    for (int r = 0; r < rounds; ++r) {
        COMPUTESET(SA_); LOADSET(SA_, s + 3);   // consumed 2 compute-steps later
        COMPUTESET(SB_); LOADSET(SB_, s + 4);
        COMPUTESET(SC_); LOADSET(SC_, s + 5);
        s += 3;
    }
#undef LOADSET
#undef COMPUTESET

    double* pc = P + (size_t)c * 64 * NOUT;
#pragma unroll
    for (int jt = 0; jt < 2; ++jt)
#pragma unroll
        for (int tt = 0; tt < 4; ++tt)
#pragma unroll
            for (int r = 0; r < 4; ++r)
                pc[(size_t)(tt * 16 + fm.rw[r]) * NOUT + (j0 + jt * 16 + fm.cl[r])] = accd[jt][tt][r];
}

// U[t][j] = sum over chunks c of P[c][t][j]  (fixed order: deterministic)
__global__ __launch_bounds__(256) void k_reduceU(const double* __restrict__ P,
                                                 double* __restrict__ U,
                                                 int nchunks, int n_out)
{
    int gid = blockIdx.x * 256 + threadIdx.x;
    int total = 64 * n_out;
    if (gid >= total) return;
    int t = gid / n_out;
    int j = gid - t * n_out;
    double s = 0.0;
    for (int c = 0; c < nchunks; ++c)
        s += P[((size_t)c * 64 + t) * n_out + j];
    U[gid] = s;
}

// Per-neuron membrane scan; emits next layer's bf16 spike fragments.
__global__ __launch_bounds__(256) void k_scan(const double* __restrict__ U,
                                              float* __restrict__ outS, // 65 x n_out
                                              u16* __restrict__ SAn,    // may be null
                                              int n_out, int shift)
{
    FragMap fm = probe_map();
    int j = blockIdx.x * 256 + threadIdx.x;
    if (j >= n_out) return;
    int g = (j & 31) >> 3, e = j & 7;
    int lanes[16];
#pragma unroll
    for (int m = 0; m < 16; ++m) lanes[m] = (fm.amode == 0) ? (g * 16 + m) : (m * 4 + g);
    u16* base = SAn ? (SAn + ((size_t)(j >> 5)) * 2048 + e) : (u16*)nullptr;
    double m = 0.0;
    outS[j] = 0.0f;                           // row 0 zero (pad_head)
#pragma unroll
    for (int t = 0; t < 64; ++t) {
        int s = t - shift;
        double u = (s >= 0) ? U[(size_t)s * n_out + j] : 0.0;
        m += u;
        bool fire = (m >= 1.0);
        m = fire ? (m - 1.0) : (m * 0.5);
        outS[(size_t)(t + 1) * n_out + j] = fire ? 1.0f : 0.0f;
        if (base) base[((t >> 4) << 9) + (lanes[t & 15] << 3)] = fire ? (u16)0x3F80 : (u16)0;
    }
}

extern "C" void kernel_launch(void* const* d_in, const int* in_sizes, int n_in_cnt,
                              void* d_out, int out_size, void* d_ws, size_t ws_size,
                              hipStream_t stream)
{
    const float* img = (const float*)d_in[0];
    const float* w1  = (const float*)d_in[1];
    const float* w2  = (const float*)d_in[2];
    const float* w3  = (const float*)d_in[3];

    const int N0 = 16384, N1 = 4096, N2 = 4096, N3 = 1024;

    float* out0 = (float*)d_out;
    float* out1 = out0 + (size_t)65 * N0;
    float* out2 = out1 + (size_t)65 * N1;
    float* out3 = out2 + (size_t)65 * N2;

    // workspace layout
    char* ws = (char*)d_ws;
    const size_t MB = 1024 * 1024;
    u16*    SA0 = (u16*)(ws);                     // 16384*64*2 = 2 MiB
    u16*    SA1 = (u16*)(ws + 2 * MB);            // 512 KiB
    u16*    SA2 = (u16*)(ws + 2 * MB + 512 * 1024);
    double* U   = (double*)(ws + 3 * MB);         // 2 MiB
    double* P   = (double*)(ws + 5 * MB);

    size_t fixed = 5 * MB;
    size_t pbudget = (ws_size > fixed) ? (ws_size - fixed) : 0;

    auto clampi = [](long v, int lo, int hi) { int x = (int)v; if (x < lo) x = lo; if (x > hi) x = hi; return x; };
    int C1 = clampi((long)(pbudget / (512ull * N1)), 1, 16);  // 128x16 = 2048 blocks
    int C2 = clampi((long)(pbudget / (512ull * N2)), 1, 8);
    int C3 = clampi((long)(pbudget / (512ull * N3)), 1, 16);

    auto ipc32 = [](int n_in, int C) { return (((n_in + C - 1) / C) + 31) & ~31; };

    // layer 0 (input): spikes + bf16 fragment-layout S0
    k_input<<<N0 / 256, 256, 0, stream>>>(img, out0, SA0, N0);

    // layer 1: U1 = S0 @ W1 (same-step spikes)
    k_gemm<4096><<<dim3(N1 / 32, C1), 64, 0, stream>>>(w1, SA0, P, N0, ipc32(N0, C1));
    k_reduceU<<<(64 * N1) / 256, 256, 0, stream>>>(P, U, C1, N1);
    k_scan<<<N1 / 256, 256, 0, stream>>>(U, out1, SA1, N1, 0);

    // layer 2: uses previous-step s1
    k_gemm<4096><<<dim3(N2 / 32, C2), 64, 0, stream>>>(w2, SA1, P, N1, ipc32(N1, C2));
    k_reduceU<<<(64 * N2) / 256, 256, 0, stream>>>(P, U, C2, N2);
    k_scan<<<N2 / 256, 256, 0, stream>>>(U, out2, SA2, N2, 1);

    // layer 3: uses previous-step s2
    k_gemm<1024><<<dim3(N3 / 32, C3), 64, 0, stream>>>(w3, SA2, P, N2, ipc32(N2, C3));
    k_reduceU<<<(64 * N3) / 256, 256, 0, stream>>>(P, U, C3, N3);
    k_scan<<<N3 / 256, 256, 0, stream>>>(U, out3, (u16*)nullptr, N3, 1);
}